// Round 6
// baseline (405.172 us; speedup 1.0000x reference)
//
#include <hip/hip_runtime.h>
#include <hip/hip_bf16.h>
#include <math.h>

#define BB 4
#define NN 2048
#define CC 3
#define HH 4
#define DD 32

typedef __attribute__((ext_vector_type(8))) short bf16x8;
typedef __attribute__((ext_vector_type(4))) float f32x4;

__device__ inline unsigned short f2bf(float x) {
    __hip_bfloat16 b = __float2bfloat16(x);
    return __builtin_bit_cast(unsigned short, b);
}

// ---------------------------------------------------------------------------
// K1: Wh = h @ W (8192x128 @ 128x128) fp32, register-tiled 2x2 per thread.
// Block = 256 thr = 4 waves; block computes 8 rows x 128 cols. Grid = 1024.
// Wave w owns rows {2w, 2w+1}; lane c2 owns cols {2c2, 2c2+1}.
// Fused src/dst head-dots via 16-lane shuffle reduce.
// ---------------------------------------------------------------------------
__global__ __launch_bounds__(256) void k1_wh(const float* __restrict__ h,
                                             const float* __restrict__ W,
                                             const float* __restrict__ a_src,
                                             const float* __restrict__ a_dst,
                                             float* __restrict__ Wh,
                                             float* __restrict__ srcv,
                                             float* __restrict__ dstv) {
    __shared__ float hrow[8][128];  // 4 KB
    int tid = threadIdx.x;
    int row0 = blockIdx.x * 8;
    int b = row0 >> 11;
    {
        int rr = tid >> 5, k4 = (tid & 31) * 4;
        *(float4*)&hrow[rr][k4] = *(const float4*)&h[(long long)(row0 + rr) * 128 + k4];
    }
    __syncthreads();
    int c2 = tid & 63;   // lane
    int r2 = tid >> 6;   // wave
    int c0 = c2 * 2;
    const float* h0p = hrow[r2 * 2];
    const float* h1p = hrow[r2 * 2 + 1];
    float a00 = 0.f, a01 = 0.f, a10 = 0.f, a11 = 0.f;
#pragma unroll
    for (int k = 0; k < 128; ++k) {
        float2 w = *(const float2*)&W[k * 128 + c0];
        float h0 = h0p[k], h1 = h1p[k];
        a00 = fmaf(h0, w.x, a00);
        a01 = fmaf(h0, w.y, a01);
        a10 = fmaf(h1, w.x, a10);
        a11 = fmaf(h1, w.y, a11);
    }
    long long rowA = row0 + r2 * 2, rowB = rowA + 1;
    *(float2*)&Wh[rowA * 128 + c0] = make_float2(a00, a01);
    *(float2*)&Wh[rowB * 128 + c0] = make_float2(a10, a11);
    float as0 = a_src[c0], as1 = a_src[c0 + 1];
    float ad0 = a_dst[c0], ad1 = a_dst[c0 + 1];
    float ps0 = a00 * as0 + a01 * as1;
    float pd0 = a00 * ad0 + a01 * ad1;
    float ps1 = a10 * as0 + a11 * as1;
    float pd1 = a10 * ad0 + a11 * ad1;
#pragma unroll
    for (int m = 1; m <= 8; m <<= 1) {
        ps0 += __shfl_xor(ps0, m);
        pd0 += __shfl_xor(pd0, m);
        ps1 += __shfl_xor(ps1, m);
        pd1 += __shfl_xor(pd1, m);
    }
    if ((c2 & 15) == 0) {
        int hh = c2 >> 4;
        int nA = (row0 & 2047) + r2 * 2;
        srcv[(b * HH + hh) * NN + nA] = ps0;
        dstv[(b * HH + hh) * NN + nA] = pd0;
        srcv[(b * HH + hh) * NN + nA + 1] = ps1;
        dstv[(b * HH + hh) * NN + nA + 1] = pd1;
    }
}

// ---------------------------------------------------------------------------
// K1t: WhT[bh][d][j] (bf16) = Wh[b][j][hh*32+d].  512 blocks x 256.
// ---------------------------------------------------------------------------
__global__ __launch_bounds__(256) void k1t(const float* __restrict__ Wh,
                                           unsigned short* __restrict__ WhT) {
    int tid = threadIdx.x;
    int wave = tid >> 6, lane = tid & 63;
    int blk = blockIdx.x;           // bh(16) x dgrp(2) x jb(16)
    int jb = blk & 15;
    int dgrp = (blk >> 4) & 1;
    int bh = blk >> 5;
    int b = bh >> 2, hh = bh & 3;
    int d = dgrp * 16 + (lane & 15);
    int jc = jb * 128 + wave * 32 + (lane >> 4) * 8;
    const float* src = Wh + ((long long)(b * NN + jc)) * 128 + hh * 32 + d;
    bf16x8 v;
#pragma unroll
    for (int i = 0; i < 8; ++i)
        v[i] = (short)f2bf(src[i * 128]);
    *(bf16x8*)&WhT[((long long)bh * 32 + d) * NN + jc] = v;
}

// ---------------------------------------------------------------------------
// K2: stream adj once (float4): bit = (c0+c1+c2 > 0). No LDS (dstv is
// L1/L2-hot) -> 8 blocks/CU occupancy, 7 independent 16B loads in flight.
// ---------------------------------------------------------------------------
__global__ __launch_bounds__(256) void k2_mask(const float* __restrict__ adj,
                                               const float* __restrict__ dstv,
                                               unsigned* __restrict__ maskb32,
                                               float* __restrict__ dmax) {
    int tid = threadIdx.x;
    int wave = tid >> 6, lane = tid & 63;
    int i = blockIdx.x * 4 + wave;   // global row 0..8191
    int b = i >> 11, il = i & 2047;
    const float* a0 = adj + ((long long)(b * CC + 0) * NN + il) * NN;
    const float* a1 = adj + ((long long)(b * CC + 1) * NN + il) * NN;
    const float* a2 = adj + ((long long)(b * CC + 2) * NN + il) * NN;
    const float4* dh0 = (const float4*)(dstv + (long long)(b * HH + 0) * NN);
    const float4* dh1 = (const float4*)(dstv + (long long)(b * HH + 1) * NN);
    const float4* dh2 = (const float4*)(dstv + (long long)(b * HH + 2) * NN);
    const float4* dh3 = (const float4*)(dstv + (long long)(b * HH + 3) * NN);
    float m0 = -INFINITY, m1 = -INFINITY, m2 = -INFINITY, m3 = -INFINITY;
    for (int jt = 0; jt < 8; ++jt) {
        int j4 = jt * 256 + lane * 4;
        float4 f0 = *(const float4*)&a0[j4];
        float4 f1 = *(const float4*)&a1[j4];
        float4 f2 = *(const float4*)&a2[j4];
        unsigned nib = (unsigned)(f0.x + f1.x + f2.x > 0.f) |
                       ((unsigned)(f0.y + f1.y + f2.y > 0.f) << 1) |
                       ((unsigned)(f0.z + f1.z + f2.z > 0.f) << 2) |
                       ((unsigned)(f0.w + f1.w + f2.w > 0.f) << 3);
        unsigned w = nib << (4 * (lane & 7));
        w |= __shfl_xor((int)w, 1);
        w |= __shfl_xor((int)w, 2);
        w |= __shfl_xor((int)w, 4);
        if ((lane & 7) == 0) maskb32[((long long)b * NN + il) * 64 + (j4 >> 5)] = w;
        int q = jt * 64 + lane;
        float4 v0 = dh0[q], v1 = dh1[q], v2 = dh2[q], v3 = dh3[q];
        m0 = fmaxf(m0, fmaxf(fmaxf((nib & 1) ? v0.x : -INFINITY, (nib & 2) ? v0.y : -INFINITY),
                             fmaxf((nib & 4) ? v0.z : -INFINITY, (nib & 8) ? v0.w : -INFINITY)));
        m1 = fmaxf(m1, fmaxf(fmaxf((nib & 1) ? v1.x : -INFINITY, (nib & 2) ? v1.y : -INFINITY),
                             fmaxf((nib & 4) ? v1.z : -INFINITY, (nib & 8) ? v1.w : -INFINITY)));
        m2 = fmaxf(m2, fmaxf(fmaxf((nib & 1) ? v2.x : -INFINITY, (nib & 2) ? v2.y : -INFINITY),
                             fmaxf((nib & 4) ? v2.z : -INFINITY, (nib & 8) ? v2.w : -INFINITY)));
        m3 = fmaxf(m3, fmaxf(fmaxf((nib & 1) ? v3.x : -INFINITY, (nib & 2) ? v3.y : -INFINITY),
                             fmaxf((nib & 4) ? v3.z : -INFINITY, (nib & 8) ? v3.w : -INFINITY)));
    }
#pragma unroll
    for (int m = 32; m >= 1; m >>= 1) {
        m0 = fmaxf(m0, __shfl_xor(m0, m));
        m1 = fmaxf(m1, __shfl_xor(m1, m));
        m2 = fmaxf(m2, __shfl_xor(m2, m));
        m3 = fmaxf(m3, __shfl_xor(m3, m));
    }
    if (lane == 0) {
        dmax[(b * HH + 0) * NN + il] = m0;
        dmax[(b * HH + 1) * NN + il] = m1;
        dmax[(b * HH + 2) * NN + il] = m2;
        dmax[(b * HH + 3) * NN + il] = m3;
    }
}

// ---------------------------------------------------------------------------
// K3: MFMA attention partials (unchanged from verified round-5 version).
// grid = (B*H)*(N/64)*2 j-halves = 1024 blocks, 4 waves x 16 rows,
// zero LDS, zero barriers.
// ---------------------------------------------------------------------------
__global__ __launch_bounds__(256) void k3_attn(const unsigned short* __restrict__ WhT,
                                               const float* __restrict__ srcv,
                                               const float* __restrict__ dstv,
                                               const float* __restrict__ dmax,
                                               const unsigned* __restrict__ maskb32,
                                               float* __restrict__ part,
                                               float* __restrict__ plsum) {
    int tid = threadIdx.x;
    int wave = tid >> 6, lane = tid & 63;
    int blk = blockIdx.x;
    int jh = blk & 1;
    int rest = blk >> 1;
    int it = rest & 31;
    int bh = rest >> 5;
    int b = bh >> 2;
    int r = lane & 15, kg = lane >> 4;
    long long bhN = (long long)bh * NN;
    int row = it * 64 + wave * 16 + r;

    float s = srcv[bhN + row];
    float dm = dmax[bhN + row];
    bool allm = !(dm > -INFINITY);
    float e0 = s + dm;
    float m = e0 > 0.f ? e0 : 0.2f * e0;
    if (allm) m = 0.f;

    const unsigned* mrow = maskb32 + ((long long)b * NN + row) * 64;
    const unsigned short* wb = WhT + (long long)bh * 32 * NN;
    const unsigned short* w0 = wb + (long long)r * NN;
    const unsigned short* w1 = wb + (long long)(16 + r) * NN;

    f32x4 acc0 = {0.f, 0.f, 0.f, 0.f};
    f32x4 acc1 = {0.f, 0.f, 0.f, 0.f};
    float psum = 0.f;

    for (int t = 0; t < 32; ++t) {
        unsigned mw = mrow[jh * 32 + t];
        int jk = jh * 1024 + t * 32 + kg * 8;
        float4 dva = *(const float4*)&dstv[bhN + jk];
        float4 dvb = *(const float4*)&dstv[bhN + jk + 4];
        float dvs[8] = {dva.x, dva.y, dva.z, dva.w, dvb.x, dvb.y, dvb.z, dvb.w};
        bf16x8 af;
#pragma unroll
        for (int i = 0; i < 8; ++i) {
            float e = s + dvs[i];
            float lr = e > 0.f ? e : 0.2f * e;
            bool bit = (mw >> (kg * 8 + i)) & 1u;
            float p = allm ? 1.f : (bit ? __expf(lr - m) : 0.f);
            psum += p;
            af[i] = (short)f2bf(p);
        }
        bf16x8 bf0 = *(const bf16x8*)&w0[jk];
        bf16x8 bf1 = *(const bf16x8*)&w1[jk];
        acc0 = __builtin_amdgcn_mfma_f32_16x16x32_bf16(af, bf0, acc0, 0, 0, 0);
        acc1 = __builtin_amdgcn_mfma_f32_16x16x32_bf16(af, bf1, acc1, 0, 0, 0);
    }

    psum += __shfl_xor(psum, 16);
    psum += __shfl_xor(psum, 32);

    long long pbase = (long long)blk * 64 + wave * 16;
#pragma unroll
    for (int reg = 0; reg < 4; ++reg) {
        int rl = kg * 4 + reg;
        part[(pbase + rl) * 32 + r] = acc0[reg];
        part[(pbase + rl) * 32 + 16 + r] = acc1[reg];
    }
    if (kg == 0) plsum[pbase + r] = psum;
}

// ---------------------------------------------------------------------------
// K4: fused reduce + normalize + (attn @ Wo + bo) + ELU.
// Block = 256 thr, 8 rows x 128 cols, register-tiled 2x2. Grid = 1024.
// Prologue builds arow[8][128] from the two j-half partials.
// ---------------------------------------------------------------------------
__global__ __launch_bounds__(256) void k4_out(const float* __restrict__ part,
                                              const float* __restrict__ plsum,
                                              const float* __restrict__ Wo,
                                              const float* __restrict__ bo,
                                              float* __restrict__ out) {
    __shared__ float arow[8][128];  // 4 KB
    int tid = threadIdx.x;
    int row0 = blockIdx.x * 8;
    int b = row0 >> 11;
#pragma unroll
    for (int q = 0; q < 4; ++q) {
        int li = q * 256 + tid;          // 0..1023
        int rr = li >> 7, c = li & 127;
        int row = row0 + rr;
        int nn = row & 2047;
        int it = nn >> 6, rl = nn & 63;
        int hh = c >> 5, d = c & 31;
        int bh = b * HH + hh;
        long long t0 = (long long)(bh * 32 + it) * 2;
        float p0 = part[(t0 * 64 + rl) * 32 + d];
        float p1 = part[((t0 + 1) * 64 + rl) * 32 + d];
        float l = plsum[t0 * 64 + rl] + plsum[(t0 + 1) * 64 + rl];
        arow[rr][c] = (p0 + p1) / l;
    }
    __syncthreads();
    int c2 = tid & 63;
    int r2 = tid >> 6;
    int c0 = c2 * 2;
    const float* h0p = arow[r2 * 2];
    const float* h1p = arow[r2 * 2 + 1];
    float a00 = bo[c0], a01 = bo[c0 + 1];
    float a10 = a00, a11 = a01;
#pragma unroll
    for (int k = 0; k < 128; ++k) {
        float2 w = *(const float2*)&Wo[k * 128 + c0];
        float h0 = h0p[k], h1 = h1p[k];
        a00 = fmaf(h0, w.x, a00);
        a01 = fmaf(h0, w.y, a01);
        a10 = fmaf(h1, w.x, a10);
        a11 = fmaf(h1, w.y, a11);
    }
    long long rowA = row0 + r2 * 2, rowB = rowA + 1;
    float o00 = a00 > 0.f ? a00 : expm1f(a00);
    float o01 = a01 > 0.f ? a01 : expm1f(a01);
    float o10 = a10 > 0.f ? a10 : expm1f(a10);
    float o11 = a11 > 0.f ? a11 : expm1f(a11);
    *(float2*)&out[rowA * 128 + c0] = make_float2(o00, o01);
    *(float2*)&out[rowB * 128 + c0] = make_float2(o10, o11);
}

extern "C" void kernel_launch(void* const* d_in, const int* in_sizes, int n_in,
                              void* d_out, int out_size, void* d_ws, size_t ws_size,
                              hipStream_t stream) {
    const float* h     = (const float*)d_in[0];
    const float* adj   = (const float*)d_in[1];
    const float* W     = (const float*)d_in[2];
    const float* a_src = (const float*)d_in[3];
    const float* a_dst = (const float*)d_in[4];
    const float* Wo    = (const float*)d_in[5];
    const float* bo    = (const float*)d_in[6];
    float* out = (float*)d_out;

    char* ws = (char*)d_ws;
    float* Wh    = (float*)(ws);                               // 4 MB
    float* srcv  = (float*)(ws + (8 << 20));                   // 128 KB
    float* dstv  = (float*)(ws + (8 << 20) + (128 << 10));     // 128 KB
    float* dmax  = (float*)(ws + (8 << 20) + (256 << 10));     // 128 KB
    unsigned* maskb32 = (unsigned*)(ws + (8 << 20) + (384 << 10));  // 2 MB
    float* part  = (float*)(ws + (10 << 20) + (384 << 10));    // 8 MB
    float* plsum = (float*)(ws + (18 << 20) + (384 << 10));    // 256 KB
    unsigned short* WhT = (unsigned short*)(ws + (18 << 20) + (640 << 10));  // 2 MB

    k1_wh<<<dim3(1024), dim3(256), 0, stream>>>(h, W, a_src, a_dst, Wh, srcv, dstv);
    k1t<<<dim3(512), dim3(256), 0, stream>>>(Wh, WhT);
    k2_mask<<<dim3(BB * NN / 4), dim3(256), 0, stream>>>(adj, dstv, maskb32, dmax);
    k3_attn<<<dim3(BB * HH * (NN / 64) * 2), dim3(256), 0, stream>>>(WhT, srcv, dstv, dmax,
                                                                     maskb32, part, plsum);
    k4_out<<<dim3(1024), dim3(256), 0, stream>>>(part, plsum, Wo, bo, out);
}